// Round 3
// baseline (9755.908 us; speedup 1.0000x reference)
//
#include <hip/hip_runtime.h>
#include <math.h>

// Problem constants (fixed by the reference)
#define T_STEPS 512
#define BATCH   64
#define HID     512
#define NROW    2048          // 4*HID rows of concatenated W
#define HHIST   16777216ULL   // T*B*H floats (offset of i_hist in d_out)

// ---------------------------------------------------------------------------
// activation helpers (fp32, clamped to avoid exp overflow)
// ---------------------------------------------------------------------------
__device__ __forceinline__ float sigf(float z) {
  z = fminf(fmaxf(z, -30.f), 30.f);
  return 1.f / (1.f + __expf(-z));
}
__device__ __forceinline__ float tanhf_(float v) {
  v = fminf(fmaxf(v, -15.f), 15.f);
  const float e = __expf(2.f * v);
  return (e - 1.f) / (e + 1.f);
}

// ---------------------------------------------------------------------------
// Kernel A: Zx[t][r][b] = b[r] + sum_k Wx[r][k] * x[t][b][k]   (unchanged)
// ---------------------------------------------------------------------------
__global__ __launch_bounds__(256) void xgemm_kernel(
    const float* __restrict__ x,
    const float* __restrict__ Wf, const float* __restrict__ Wi,
    const float* __restrict__ Wo, const float* __restrict__ Wc,
    const float* __restrict__ bf, const float* __restrict__ bi,
    const float* __restrict__ bo, const float* __restrict__ bc,
    float* __restrict__ Zx)
{
  const int rtile = blockIdx.x;   // 0..15
  const int t     = blockIdx.y;   // 0..511
  const int g  = rtile >> 2;
  const int n0 = (rtile & 3) * 128;
  const float* Wg = (g == 0) ? Wf : (g == 1) ? Wi : (g == 2) ? Wo : Wc;
  const float* bg = (g == 0) ? bf : (g == 1) ? bi : (g == 2) ? bo : bc;

  __shared__ float Wt[32][132];   // [k][r] transposed, padded
  __shared__ float Xt[32][68];    // [k][b] transposed, padded

  const int tid = threadIdx.x;
  const int tr  = tid & 31;       // 4 r-rows each
  const int tb  = tid >> 5;       // 8 b-cols each

  float acc[4][8];
#pragma unroll
  for (int i = 0; i < 4; ++i)
#pragma unroll
    for (int j = 0; j < 8; ++j) acc[i][j] = 0.f;

  float biasv[4];
#pragma unroll
  for (int i = 0; i < 4; ++i) biasv[i] = bg[n0 + tr * 4 + i];

  const float* xt = x + (size_t)t * (BATCH * 512);

  for (int kc = 0; kc < 512; kc += 32) {
#pragma unroll
    for (int p = 0; p < 4; ++p) {
      const int r  = p * 32 + (tid >> 3);
      const int kk = (tid & 7) * 4;
      float4 v = *(const float4*)&Wg[(size_t)(n0 + r) * 1024 + 512 + kc + kk];
      Wt[kk + 0][r] = v.x; Wt[kk + 1][r] = v.y;
      Wt[kk + 2][r] = v.z; Wt[kk + 3][r] = v.w;
    }
    {
      const int b  = tid >> 2;
      const int kk = (tid & 3) * 8;
      float4 v0 = *(const float4*)&xt[b * 512 + kc + kk];
      float4 v1 = *(const float4*)&xt[b * 512 + kc + kk + 4];
      Xt[kk + 0][b] = v0.x; Xt[kk + 1][b] = v0.y;
      Xt[kk + 2][b] = v0.z; Xt[kk + 3][b] = v0.w;
      Xt[kk + 4][b] = v1.x; Xt[kk + 5][b] = v1.y;
      Xt[kk + 6][b] = v1.z; Xt[kk + 7][b] = v1.w;
    }
    __syncthreads();
#pragma unroll
    for (int kk = 0; kk < 32; ++kk) {
      float4 wv = *(const float4*)&Wt[kk][tr * 4];
      float4 x0 = *(const float4*)&Xt[kk][tb * 8];
      float4 x1 = *(const float4*)&Xt[kk][tb * 8 + 4];
      const float wa[4] = {wv.x, wv.y, wv.z, wv.w};
      const float xa[8] = {x0.x, x0.y, x0.z, x0.w, x1.x, x1.y, x1.z, x1.w};
#pragma unroll
      for (int i = 0; i < 4; ++i)
#pragma unroll
        for (int j = 0; j < 8; ++j)
          acc[i][j] = fmaf(wa[i], xa[j], acc[i][j]);
    }
    __syncthreads();
  }

  const int rg = g * 512 + n0 + tr * 4;
#pragma unroll
  for (int ir = 0; ir < 4; ++ir) {
    const float bv = biasv[ir];
    float4 o0 = make_float4(acc[ir][0] + bv, acc[ir][1] + bv,
                            acc[ir][2] + bv, acc[ir][3] + bv);
    float4 o1 = make_float4(acc[ir][4] + bv, acc[ir][5] + bv,
                            acc[ir][6] + bv, acc[ir][7] + bv);
    float* dst = Zx + ((size_t)t * NROW + rg + ir) * 64 + tb * 8;
    *(float4*)dst       = o0;
    *(float4*)(dst + 4) = o1;
  }
}

// ---------------------------------------------------------------------------
// Grid barrier: 16 groups x 16 wgs, RELAXED polling. Fences kept (each wg's
// leader fences its own CU L1 / XCD L2) but they are now near-free: hT goes
// write-through (sc1 atomic stores) and out goes nontemporal, so the release
// writeback has ~nothing dirty to flush.
// ---------------------------------------------------------------------------
__device__ __forceinline__ void grid_barrier(unsigned* cnt, int w, int tid, int round) {
  __syncthreads();   // all waves' stores drained (vmcnt 0) before arrival
  if (tid == 0) {
    __builtin_amdgcn_fence(__ATOMIC_RELEASE, "agent");
    unsigned* gc = cnt + 16 + ((w >> 4) << 5);           // 128B-spaced group counters
    unsigned prev = __hip_atomic_fetch_add(gc, 1u, __ATOMIC_RELAXED,
                                           __HIP_MEMORY_SCOPE_AGENT);
    if ((prev & 15u) == 15u)
      __hip_atomic_fetch_add(cnt, 1u, __ATOMIC_RELAXED,
                             __HIP_MEMORY_SCOPE_AGENT);
    const unsigned target = (unsigned)(round + 1) * 16u;
    while (__hip_atomic_load(cnt, __ATOMIC_RELAXED,
                             __HIP_MEMORY_SCOPE_AGENT) < target)
      __builtin_amdgcn_s_sleep(2);
    __builtin_amdgcn_fence(__ATOMIC_ACQUIRE, "agent");
  }
  __syncthreads();
}

// ---------------------------------------------------------------------------
// Kernel B (fast path): persistent cooperative recurrence, 256 wgs x 512 thr.
// wg w owns hidden units {n0, n0+1}, n0 = (w&7)*64 + (w>>3)*2 (XCD-grouped).
// Thread map: ks = tid>>4 (32 k-slices of 16), b4 = (tid&15)*4 (4 batch each).
// One W float4 read feeds 16 FMAs (4x less LDS traffic than round 2).
// h exchange: [n][b] global buffer; producers store write-through (agent
// relaxed atomics), consumers re-read after the barrier's acquire fence.
// out stores are nontemporal (no L2 dirtying).
// ---------------------------------------------------------------------------
__global__ __launch_bounds__(512) void lstm_rec_fast(
    const float* __restrict__ mask,
    const float* __restrict__ Wf, const float* __restrict__ Wi,
    const float* __restrict__ Wo, const float* __restrict__ Wc,
    const float* __restrict__ Zx,
    float* __restrict__ hT, unsigned* __restrict__ cnt,
    float* __restrict__ out)
{
  __shared__ float Wlds[8 * 512];          // 16 KB (h-part rows of 8 gates)
  __shared__ float zpart[8][32][72];       // 73.7 KB, padded: 2-way banks only

  const int tid = threadIdx.x;
  const int w   = blockIdx.x;              // 0..255
  const int ks  = tid >> 4;                // 0..31 (16-wide k slice)
  const int b4  = (tid & 15) << 2;         // 0,4,...,60
  const int n0  = ((w & 7) << 6) + ((w >> 3) << 1);

  // preload this wg's 8 W rows (h-part, cols [0,512))
#pragma unroll
  for (int i = 0; i < 2; ++i) {
    const int idx4 = tid + (i << 9);       // 0..1023 -> 8 rows x 128 float4
    const int rr   = idx4 >> 7;
    const int col  = (idx4 & 127) << 2;
    const int g = rr >> 1, u = rr & 1;
    const float* Wrow =
        ((g == 0) ? Wf : (g == 1) ? Wi : (g == 2) ? Wo : Wc) +
        (size_t)(n0 + u) * 1024;
    *(float4*)&Wlds[rr * 512 + col] = *(const float4*)&Wrow[col];
  }

  const int u  = tid >> 6;                 // reducer role (tid < 128)
  const int bb = tid & 63;
  float c_r = 0.f, h_r = 0.f;
  float zpre[4] = {0.f, 0.f, 0.f, 0.f};
  float mval = 0.f;
  if (tid < 128) {                         // prefetch step 0
    mval = mask[bb];
#pragma unroll
    for (int g = 0; g < 4; ++g)
      zpre[g] = Zx[((size_t)(g * 512 + n0 + u)) * 64 + bb];
  }
  __syncthreads();

  for (int t = 0; t < T_STEPS; ++t) {
    // ---- load this thread's h tile: 16 float4 (4 b-cols x 16 k-rows)
    const float* hcur = hT + ((t & 1) << 15);
    float4 hv[16];
#pragma unroll
    for (int kk = 0; kk < 16; ++kk)
      hv[kk] = *(const float4*)(hcur + (ks * 16 + kk) * 64 + b4);

    float acc[8][4];
#pragma unroll
    for (int rr = 0; rr < 8; ++rr)
#pragma unroll
      for (int j = 0; j < 4; ++j) acc[rr][j] = 0.f;

#pragma unroll
    for (int kq4 = 0; kq4 < 4; ++kq4) {
#pragma unroll
      for (int rr = 0; rr < 8; ++rr) {
        const float4 wv = *(const float4*)&Wlds[rr * 512 + ks * 16 + kq4 * 4];
        const float wk[4] = {wv.x, wv.y, wv.z, wv.w};
#pragma unroll
        for (int dk = 0; dk < 4; ++dk) {
          const float4 hh = hv[kq4 * 4 + dk];
          acc[rr][0] = fmaf(wk[dk], hh.x, acc[rr][0]);
          acc[rr][1] = fmaf(wk[dk], hh.y, acc[rr][1]);
          acc[rr][2] = fmaf(wk[dk], hh.z, acc[rr][2]);
          acc[rr][3] = fmaf(wk[dk], hh.w, acc[rr][3]);
        }
      }
    }

#pragma unroll
    for (int rr = 0; rr < 8; ++rr)
      *(float4*)&zpart[rr][ks][b4] =
          make_float4(acc[rr][0], acc[rr][1], acc[rr][2], acc[rr][3]);
    __syncthreads();   // zpart complete

    if (tid < 128) {
      float z[4];
#pragma unroll
      for (int g = 0; g < 4; ++g) {
        float s = zpre[g];
#pragma unroll 8
        for (int q = 0; q < 32; ++q) s += zpart[g * 2 + u][q][bb];
        z[g] = s;
      }
      const float f  = sigf(z[0]);
      const float ig = sigf(z[1]);
      const float o  = sigf(z[2]);
      const float ct = tanhf_(z[3]);
      float cn = f * c_r + ig * ct;
      cn = mval * cn + (1.f - mval) * c_r;
      c_r = cn;
      float hn = o * tanhf_(cn);
      hn = mval * hn + (1.f - mval) * h_r;
      h_r = hn;
      const int n = n0 + u;
      // write-through store: at coherence point once vmcnt drains (syncthreads)
      __hip_atomic_store(&hT[(((t + 1) & 1) << 15) + n * 64 + bb], hn,
                         __ATOMIC_RELAXED, __HIP_MEMORY_SCOPE_AGENT);
      // nontemporal out stores: never dirty L2 -> release fence stays cheap
      __builtin_nontemporal_store(hn, &out[((size_t)t * 64 + bb) * 512 + n]);
      __builtin_nontemporal_store(ig, &out[HHIST + ((size_t)t * 64 + bb) * 512 + n]);
      // prefetch t+1's x-part / mask: latency hides under the barrier wait
      if (t + 1 < T_STEPS) {
        mval = mask[(t + 1) * 64 + bb];
#pragma unroll
        for (int g = 0; g < 4; ++g)
          zpre[g] = Zx[((size_t)(t + 1) * NROW + g * 512 + n) * 64 + bb];
      }
    }

    if (t != T_STEPS - 1) grid_barrier(cnt, w, tid, t);
  }
}

// ---------------------------------------------------------------------------
// Kernel B (fallback, ws too small): round-2 inline-x version, verbatim.
// ---------------------------------------------------------------------------
__global__ __launch_bounds__(512) void lstm_rec_inline(
    const float* __restrict__ x,  const float* __restrict__ mask,
    const float* __restrict__ Wf, const float* __restrict__ Wi,
    const float* __restrict__ Wo, const float* __restrict__ Wc,
    const float* __restrict__ bf, const float* __restrict__ bi,
    const float* __restrict__ bo, const float* __restrict__ bc,
    float* __restrict__ hT, unsigned* __restrict__ cnt,
    float* __restrict__ out)
{
  constexpr int WC = 1024;
  __shared__ float Wlds[8 * WC];
  __shared__ float zpart[8 * 8 * 64];

  const int tid = threadIdx.x;
  const int w   = blockIdx.x;
  const int kq  = tid >> 6;
  const int b   = tid & 63;
  const int n0  = ((w & 7) << 6) + ((w >> 3) << 1);

#pragma unroll
  for (int i = 0; i < WC / 256; ++i) {
    const int idx4 = tid + (i << 9);
    const int rr   = idx4 / (WC / 4);
    const int col  = (idx4 % (WC / 4)) * 4;
    const int g = rr >> 1, u = rr & 1;
    const float* Wrow =
        ((g == 0) ? Wf : (g == 1) ? Wi : (g == 2) ? Wo : Wc) +
        (size_t)(n0 + u) * 1024;
    *(float4*)&Wlds[rr * WC + col] = *(const float4*)&Wrow[col];
  }

  float biasv[4] = {0.f, 0.f, 0.f, 0.f};
  float c_r = 0.f, h_r = 0.f;
  if (tid < 128) {
    const int u = tid >> 6;
    biasv[0] = bf[n0 + u]; biasv[1] = bi[n0 + u];
    biasv[2] = bo[n0 + u]; biasv[3] = bc[n0 + u];
  }
  __syncthreads();

  for (int t = 0; t < T_STEPS; ++t) {
    float zpre[4] = {0.f, 0.f, 0.f, 0.f};
    float mval = 0.f;
    if (tid < 128) {
      const int bb = tid & 63;
      mval = mask[t * 64 + bb];
#pragma unroll
      for (int g = 0; g < 4; ++g) zpre[g] = biasv[g];
    }

    float acc[8];
#pragma unroll
    for (int rr = 0; rr < 8; ++rr) acc[rr] = 0.f;

    {
      const float* hcur = hT + ((t & 1) << 15);
      const int k0 = kq << 6;
#pragma unroll
      for (int k4 = 0; k4 < 16; ++k4) {
        const int k = k0 + (k4 << 2);
        const float h0 = hcur[(k + 0) * 64 + b];
        const float h1 = hcur[(k + 1) * 64 + b];
        const float h2 = hcur[(k + 2) * 64 + b];
        const float h3 = hcur[(k + 3) * 64 + b];
#pragma unroll
        for (int rr = 0; rr < 8; ++rr) {
          float4 wv = *(const float4*)&Wlds[rr * WC + k];
          acc[rr] = fmaf(h0, wv.x, acc[rr]);
          acc[rr] = fmaf(h1, wv.y, acc[rr]);
          acc[rr] = fmaf(h2, wv.z, acc[rr]);
          acc[rr] = fmaf(h3, wv.w, acc[rr]);
        }
      }
    }
    {
      const float* xt = x + (size_t)t * (64 * 512) + b * 512;
      const int k0 = kq << 6;
#pragma unroll
      for (int k4 = 0; k4 < 16; ++k4) {
        const int k = k0 + (k4 << 2);
        float4 xv = *(const float4*)&xt[k];
#pragma unroll
        for (int rr = 0; rr < 8; ++rr) {
          float4 wv = *(const float4*)&Wlds[rr * WC + 512 + k];
          acc[rr] = fmaf(xv.x, wv.x, acc[rr]);
          acc[rr] = fmaf(xv.y, wv.y, acc[rr]);
          acc[rr] = fmaf(xv.z, wv.z, acc[rr]);
          acc[rr] = fmaf(xv.w, wv.w, acc[rr]);
        }
      }
    }

#pragma unroll
    for (int rr = 0; rr < 8; ++rr)
      zpart[((kq << 3) + rr) * 64 + b] = acc[rr];
    __syncthreads();

    if (tid < 128) {
      const int u = tid >> 6, bb = tid & 63;
      float z[4];
#pragma unroll
      for (int g = 0; g < 4; ++g) {
        const int rr = g * 2 + u;
        float s = zpre[g];
#pragma unroll
        for (int q = 0; q < 8; ++q) s += zpart[((q << 3) + rr) * 64 + bb];
        z[g] = s;
      }
      const float f  = sigf(z[0]);
      const float ig = sigf(z[1]);
      const float o  = sigf(z[2]);
      const float ct = tanhf_(z[3]);
      float cn = f * c_r + ig * ct;
      cn = mval * cn + (1.f - mval) * c_r;
      c_r = cn;
      float hn = o * tanhf_(cn);
      hn = mval * hn + (1.f - mval) * h_r;
      h_r = hn;
      const int n = n0 + u;
      hT[(((t + 1) & 1) << 15) + n * 64 + bb] = hn;
      out[((size_t)t * 64 + bb) * 512 + n]         = hn;
      out[HHIST + ((size_t)t * 64 + bb) * 512 + n] = ig;
    }

    if (t != T_STEPS - 1) grid_barrier(cnt, w, tid, t);
  }
}

// ---------------------------------------------------------------------------
// launch
// ---------------------------------------------------------------------------
extern "C" void kernel_launch(void* const* d_in, const int* in_sizes, int n_in,
                              void* d_out, int out_size, void* d_ws, size_t ws_size,
                              hipStream_t stream) {
  (void)in_sizes; (void)n_in; (void)out_size;
  // setup_inputs order: x, mask, Wf, bf, Wi, bi, Wc, bc, Wo, bo
  const float* x    = (const float*)d_in[0];
  const float* mask = (const float*)d_in[1];
  const float* Wf   = (const float*)d_in[2];
  const float* bf   = (const float*)d_in[3];
  const float* Wi   = (const float*)d_in[4];
  const float* bi   = (const float*)d_in[5];
  const float* Wc   = (const float*)d_in[6];
  const float* bc   = (const float*)d_in[7];
  const float* Wo   = (const float*)d_in[8];
  const float* bo   = (const float*)d_in[9];
  float* out = (float*)d_out;

  const size_t zx_bytes  = (size_t)T_STEPS * NROW * 64 * 4;   // 256 MiB
  const size_t h_bytes   = 2 * 64 * 512 * 4;                  // 256 KiB
  const size_t bar_bytes = 4096;
  const bool fast = ws_size >= zx_bytes + h_bytes + bar_bytes;

  float* Zx; float* hT;
  if (fast) {
    Zx = (float*)d_ws;
    hT = (float*)((char*)d_ws + zx_bytes);
  } else {
    Zx = nullptr;
    hT = (float*)d_ws;
  }
  unsigned* cnt = (unsigned*)((char*)hT + h_bytes);

  // zero h double-buffer + barrier counters every launch (deterministic)
  hipMemsetAsync(hT, 0, h_bytes + bar_bytes, stream);

  if (fast) {
    hipLaunchKernelGGL(xgemm_kernel, dim3(16, 512), dim3(256), 0, stream,
                       x, Wf, Wi, Wo, Wc, bf, bi, bo, bc, Zx);
    void* kargs[] = { (void*)&mask, (void*)&Wf, (void*)&Wi, (void*)&Wo,
                      (void*)&Wc, (void*)&Zx, (void*)&hT, (void*)&cnt,
                      (void*)&out };
    hipLaunchCooperativeKernel(reinterpret_cast<void*>(&lstm_rec_fast),
                               dim3(256), dim3(512), kargs, 0, stream);
  } else {
    void* kargs[] = { (void*)&x, (void*)&mask, (void*)&Wf, (void*)&Wi,
                      (void*)&Wo, (void*)&Wc, (void*)&bf, (void*)&bi,
                      (void*)&bo, (void*)&bc, (void*)&hT, (void*)&cnt,
                      (void*)&out };
    hipLaunchCooperativeKernel(reinterpret_cast<void*>(&lstm_rec_inline),
                               dim3(256), dim3(512), kargs, 0, stream);
  }
}

// Round 5
// 7994.437 us; speedup vs baseline: 1.2203x; 1.2203x over previous
//
#include <hip/hip_runtime.h>
#include <math.h>

// Problem constants (fixed by the reference)
#define T_STEPS 512
#define BATCH   64
#define HID     512
#define NROW    2048          // 4*HID rows of concatenated W
#define HHIST   16777216ULL   // T*B*H floats (offset of i_hist in d_out)

// ---------------------------------------------------------------------------
// activation helpers (fp32, clamped to avoid exp overflow)
// ---------------------------------------------------------------------------
__device__ __forceinline__ float sigf(float z) {
  z = fminf(fmaxf(z, -30.f), 30.f);
  return 1.f / (1.f + __expf(-z));
}
__device__ __forceinline__ float tanhf_(float v) {
  v = fminf(fmaxf(v, -15.f), 15.f);
  const float e = __expf(2.f * v);
  return (e - 1.f) / (e + 1.f);
}

// ---------------------------------------------------------------------------
// Kernel A: Zx[t][g][r][b8] = b[r] + sum_k Wx[r][k] * x[t][g*8+b8][k]
// Layout [t][batch-group g][2048 rows][8 b]: each lstm group reads dense,
// single-XCD cache lines.
// ---------------------------------------------------------------------------
__global__ __launch_bounds__(256) void xgemm_kernel(
    const float* __restrict__ x,
    const float* __restrict__ Wf, const float* __restrict__ Wi,
    const float* __restrict__ Wo, const float* __restrict__ Wc,
    const float* __restrict__ bf, const float* __restrict__ bi,
    const float* __restrict__ bo, const float* __restrict__ bc,
    float* __restrict__ Zx)
{
  const int rtile = blockIdx.x;   // 0..15
  const int t     = blockIdx.y;   // 0..511
  const int g  = rtile >> 2;
  const int n0 = (rtile & 3) * 128;
  const float* Wg = (g == 0) ? Wf : (g == 1) ? Wi : (g == 2) ? Wo : Wc;
  const float* bg = (g == 0) ? bf : (g == 1) ? bi : (g == 2) ? bo : bc;

  __shared__ float Wt[32][132];   // [k][r] transposed, padded
  __shared__ float Xt[32][68];    // [k][b] transposed, padded

  const int tid = threadIdx.x;
  const int tr  = tid & 31;       // 4 r-rows each
  const int tb  = tid >> 5;       // 8 b-cols each (= batch group tb)

  float acc[4][8];
#pragma unroll
  for (int i = 0; i < 4; ++i)
#pragma unroll
    for (int j = 0; j < 8; ++j) acc[i][j] = 0.f;

  float biasv[4];
#pragma unroll
  for (int i = 0; i < 4; ++i) biasv[i] = bg[n0 + tr * 4 + i];

  const float* xt = x + (size_t)t * (BATCH * 512);

  for (int kc = 0; kc < 512; kc += 32) {
#pragma unroll
    for (int p = 0; p < 4; ++p) {
      const int r  = p * 32 + (tid >> 3);
      const int kk = (tid & 7) * 4;
      float4 v = *(const float4*)&Wg[(size_t)(n0 + r) * 1024 + 512 + kc + kk];
      Wt[kk + 0][r] = v.x; Wt[kk + 1][r] = v.y;
      Wt[kk + 2][r] = v.z; Wt[kk + 3][r] = v.w;
    }
    {
      const int b  = tid >> 2;
      const int kk = (tid & 3) * 8;
      float4 v0 = *(const float4*)&xt[b * 512 + kc + kk];
      float4 v1 = *(const float4*)&xt[b * 512 + kc + kk + 4];
      Xt[kk + 0][b] = v0.x; Xt[kk + 1][b] = v0.y;
      Xt[kk + 2][b] = v0.z; Xt[kk + 3][b] = v0.w;
      Xt[kk + 4][b] = v1.x; Xt[kk + 5][b] = v1.y;
      Xt[kk + 6][b] = v1.z; Xt[kk + 7][b] = v1.w;
    }
    __syncthreads();
#pragma unroll
    for (int kk = 0; kk < 32; ++kk) {
      float4 wv = *(const float4*)&Wt[kk][tr * 4];
      float4 x0 = *(const float4*)&Xt[kk][tb * 8];
      float4 x1 = *(const float4*)&Xt[kk][tb * 8 + 4];
      const float wa[4] = {wv.x, wv.y, wv.z, wv.w};
      const float xa[8] = {x0.x, x0.y, x0.z, x0.w, x1.x, x1.y, x1.z, x1.w};
#pragma unroll
      for (int i = 0; i < 4; ++i)
#pragma unroll
        for (int j = 0; j < 8; ++j)
          acc[i][j] = fmaf(wa[i], xa[j], acc[i][j]);
    }
    __syncthreads();
  }

  const int rg = g * 512 + n0 + tr * 4;
#pragma unroll
  for (int ir = 0; ir < 4; ++ir) {
    const float bv = biasv[ir];
    float4 o0 = make_float4(acc[ir][0] + bv, acc[ir][1] + bv,
                            acc[ir][2] + bv, acc[ir][3] + bv);
    float4 o1 = make_float4(acc[ir][4] + bv, acc[ir][5] + bv,
                            acc[ir][6] + bv, acc[ir][7] + bv);
    // [t][g=tb][row][8b] layout
    float* dst = Zx + (((size_t)t * 8 + tb) * NROW + rg + ir) * 8;
    *(float4*)dst       = o0;
    *(float4*)(dst + 4) = o1;
  }
}

// ---------------------------------------------------------------------------
// Kernel B (fast): 8 independent batch-groups of 32 wgs; NO grid barrier.
// wg w: group g = w&7 (batch slice [8g,8g+8)), unit block i = w>>3
// (units [16i,16i+16)). Wave wv owns units {16i+2wv, 16i+2wv+1} x 4 gates;
// its 8 W rows (h-part) live in REGISTERS (Wreg[8][8], k-slice = 8*lane..+8).
// Per step: poll 32 producer flags (relaxed agent atomics) -> stage group h
// slice (16KB) into LDS via CP-coherent b64 atomic loads -> register dot
// -> in-wave reduce-scatter (keep/send halves!) -> gates -> write-through h
// + release flag. Correctness never depends on wg->XCD placement.
// ---------------------------------------------------------------------------
__global__ __launch_bounds__(512, 2) void lstm_rec_fast(
    const float* __restrict__ mask,
    const float* __restrict__ Wf, const float* __restrict__ Wi,
    const float* __restrict__ Wo, const float* __restrict__ Wc,
    const float* __restrict__ Zx,
    float* __restrict__ hT, unsigned* __restrict__ flags,
    float* __restrict__ out)
{
  __shared__ float hlds[4096];   // 1024 b128 slots (swizzled), 16 KB

  const int tid  = threadIdx.x;
  const int w    = blockIdx.x;        // 0..255
  const int g    = w & 7;             // batch group
  const int ib   = w >> 3;            // unit block 0..31
  const int wv   = tid >> 6;          // wave 0..7
  const int lane = tid & 63;

  const int unit0 = ib * 16 + wv * 2; // this wave's two units
  // lane's final output index after reduce-scatter: lane = r_local*8 + b
  const int g4l = lane >> 4;          // gate 0..3 (f,i,o,c)
  const int u2l = (lane >> 3) & 1;    // unit parity
  const int bl  = lane & 7;           // batch within group

  // ---- W preload into registers: Wreg[r][j] = Wgate[g4][unit0+u2][8*lane+j]
  float Wreg[8][8];
  {
    const float* Wm[4] = {Wf, Wi, Wo, Wc};
#pragma unroll
    for (int g4 = 0; g4 < 4; ++g4)
#pragma unroll
      for (int u2 = 0; u2 < 2; ++u2) {
        const float* row = Wm[g4] + (size_t)(unit0 + u2) * 1024 + lane * 8;
        float4 a = *(const float4*)row;
        float4 b = *(const float4*)(row + 4);
        float* Wr = Wreg[g4 * 2 + u2];
        Wr[0] = a.x; Wr[1] = a.y; Wr[2] = a.z; Wr[3] = a.w;
        Wr[4] = b.x; Wr[5] = b.y; Wr[6] = b.z; Wr[7] = b.w;
      }
  }

  float c_r = 0.f, h_r = 0.f;          // live in lanes 0..15 only
  const int base16 = lane << 4;        // 16*lane (LDS slot base)

  for (int t = 0; t < T_STEPS; ++t) {
    // ---- issue x-part + mask loads early (plain cached; consumed after dot)
    const float zpre = Zx[(((size_t)t * 8 + g) * NROW +
                           g4l * 512 + unit0 + u2l) * 8 + bl];
    const float mval = mask[t * 64 + g * 8 + bl];

    // ---- wait for all 32 producers of this group to publish h^t
    if (t > 0 && wv == 0) {
      const unsigned tgt = (unsigned)t;
      const unsigned fidx = (unsigned)(g + 8 * (lane & 31));
      while (true) {
        unsigned f = __hip_atomic_load(&flags[fidx], __ATOMIC_RELAXED,
                                       __HIP_MEMORY_SCOPE_AGENT);
        if (__all((lane >= 32) | (f >= tgt))) break;
        __builtin_amdgcn_s_sleep(1);
      }
    }
    __syncthreads();   // also fences step t-1's hlds reads vs re-stage below

    // ---- stage h^t (group slice, 512 k x 8 b) into LDS, CP-coherent loads.
    // thread tid handles k = tid; slot s = 2k+half, phys = (s&~7)|((s+(s>>4))&7)
    {
      const int buf = t & 1;
      const unsigned long long* hq =
          (const unsigned long long*)hT + ((size_t)(buf * 8 + g) * 512 + tid) * 4;
      unsigned long long q0 = __hip_atomic_load(hq + 0, __ATOMIC_RELAXED,
                                                __HIP_MEMORY_SCOPE_AGENT);
      unsigned long long q1 = __hip_atomic_load(hq + 1, __ATOMIC_RELAXED,
                                                __HIP_MEMORY_SCOPE_AGENT);
      unsigned long long q2 = __hip_atomic_load(hq + 2, __ATOMIC_RELAXED,
                                                __HIP_MEMORY_SCOPE_AGENT);
      unsigned long long q3 = __hip_atomic_load(hq + 3, __ATOMIC_RELAXED,
                                                __HIP_MEMORY_SCOPE_AGENT);
      float4 lo = make_float4(__uint_as_float((unsigned)q0),
                              __uint_as_float((unsigned)(q0 >> 32)),
                              __uint_as_float((unsigned)q1),
                              __uint_as_float((unsigned)(q1 >> 32)));
      float4 hi = make_float4(__uint_as_float((unsigned)q2),
                              __uint_as_float((unsigned)(q2 >> 32)),
                              __uint_as_float((unsigned)q3),
                              __uint_as_float((unsigned)(q3 >> 32)));
      const int s0 = tid * 2, s1 = s0 + 1;
      const int p0 = (s0 & ~7) | ((s0 + (s0 >> 4)) & 7);
      const int p1 = (s1 & ~7) | ((s1 + (s1 >> 4)) & 7);
      *(float4*)&hlds[p0 * 4] = lo;
      *(float4*)&hlds[p1 * 4] = hi;
    }
    __syncthreads();

    // ---- dot: v[r*8+b] = sum over lane's 8 k of Wreg[r][j] * h[k][b]
    float v[64];
#pragma unroll
    for (int q = 0; q < 64; ++q) v[q] = 0.f;

#pragma unroll
    for (int j = 0; j < 8; ++j) {
      const int s0 = base16 + 2 * j, s1 = s0 + 1;
      const int p0 = (s0 & ~7) | ((s0 + lane) & 7);   // s>>4 == lane here
      const int p1 = (s1 & ~7) | ((s1 + lane) & 7);
      const float4 h0 = *(const float4*)&hlds[p0 * 4]; // h[k][0..3]
      const float4 h1 = *(const float4*)&hlds[p1 * 4]; // h[k][4..7]
#pragma unroll
      for (int r = 0; r < 8; ++r) {
        const float wr = Wreg[r][j];
        v[r * 8 + 0] = fmaf(wr, h0.x, v[r * 8 + 0]);
        v[r * 8 + 1] = fmaf(wr, h0.y, v[r * 8 + 1]);
        v[r * 8 + 2] = fmaf(wr, h0.z, v[r * 8 + 2]);
        v[r * 8 + 3] = fmaf(wr, h0.w, v[r * 8 + 3]);
        v[r * 8 + 4] = fmaf(wr, h1.x, v[r * 8 + 4]);
        v[r * 8 + 5] = fmaf(wr, h1.y, v[r * 8 + 5]);
        v[r * 8 + 6] = fmaf(wr, h1.z, v[r * 8 + 6]);
        v[r * 8 + 7] = fmaf(wr, h1.w, v[r * 8 + 7]);
      }
    }

    // ---- in-wave reduce-scatter over 64 lanes: lane l ends with z[index l].
    // Recursive halving: KEEP your own half, SEND the complementary half.
    // (Round-4 bug: sent the kept half -> scrambled sums.)
#pragma unroll
    for (int m = 0; m < 6; ++m) {
      const int lb = (lane >> m) & 1;
#pragma unroll
      for (int p = 0; p < (32 >> m); ++p) {
        const float keep = lb ? v[2 * p + 1] : v[2 * p];
        const float send = lb ? v[2 * p]     : v[2 * p + 1];
        v[p] = keep + __shfl_xor(send, 1 << m, 64);
      }
    }
    const float z = v[0] + zpre;

    // gather the 4 gate z's of (u2l, bl) to lanes 0..15
    const float zi_ = __shfl(z, lane + 16, 64);
    const float zo_ = __shfl(z, lane + 32, 64);
    const float zc_ = __shfl(z, lane + 48, 64);

    const float f  = sigf(z);      // lanes 0..15: z is the f-gate z
    const float ig = sigf(zi_);
    const float o  = sigf(zo_);
    const float ct = tanhf_(zc_);
    float cn = f * c_r + ig * ct;
    cn = mval * cn + (1.f - mval) * c_r;
    float hn = o * tanhf_(cn);
    hn = mval * hn + (1.f - mval) * h_r;

    if (lane < 16) {
      c_r = cn; h_r = hn;
      const int n = unit0 + u2l;
      // write-through h for next step (CP-coherent)
      const size_t hidx = ((size_t)(((t + 1) & 1) * 8 + g) * 512 + n) * 8 + bl;
      __hip_atomic_store((unsigned*)&hT[hidx], __float_as_uint(hn),
                         __ATOMIC_RELAXED, __HIP_MEMORY_SCOPE_AGENT);
      // history outputs (nontemporal: keep L2 clean)
      const size_t ob = ((size_t)t * 64 + g * 8 + bl) * 512 + n;
      __builtin_nontemporal_store(hn, &out[ob]);
      __builtin_nontemporal_store(ig, &out[HHIST + ob]);
    }

    if (t + 1 < T_STEPS) {
      __syncthreads();   // all waves' h stores drained (vmcnt 0)
      if (tid == 0)
        __hip_atomic_fetch_add(&flags[w], 1u, __ATOMIC_RELEASE,
                               __HIP_MEMORY_SCOPE_AGENT);
    }
  }
}

// ---------------------------------------------------------------------------
// Fallback (ws too small): round-3 inline-x cooperative version, verbatim.
// ---------------------------------------------------------------------------
__device__ __forceinline__ void grid_barrier(unsigned* cnt, int w, int tid, int round) {
  __syncthreads();
  if (tid == 0) {
    __builtin_amdgcn_fence(__ATOMIC_RELEASE, "agent");
    unsigned* gc = cnt + 16 + ((w >> 4) << 5);
    unsigned prev = __hip_atomic_fetch_add(gc, 1u, __ATOMIC_RELAXED,
                                           __HIP_MEMORY_SCOPE_AGENT);
    if ((prev & 15u) == 15u)
      __hip_atomic_fetch_add(cnt, 1u, __ATOMIC_RELAXED,
                             __HIP_MEMORY_SCOPE_AGENT);
    const unsigned target = (unsigned)(round + 1) * 16u;
    while (__hip_atomic_load(cnt, __ATOMIC_RELAXED,
                             __HIP_MEMORY_SCOPE_AGENT) < target)
      __builtin_amdgcn_s_sleep(2);
    __builtin_amdgcn_fence(__ATOMIC_ACQUIRE, "agent");
  }
  __syncthreads();
}

__global__ __launch_bounds__(512) void lstm_rec_inline(
    const float* __restrict__ x,  const float* __restrict__ mask,
    const float* __restrict__ Wf, const float* __restrict__ Wi,
    const float* __restrict__ Wo, const float* __restrict__ Wc,
    const float* __restrict__ bf, const float* __restrict__ bi,
    const float* __restrict__ bo, const float* __restrict__ bc,
    float* __restrict__ hT, unsigned* __restrict__ cnt,
    float* __restrict__ out)
{
  constexpr int WC = 1024;
  __shared__ float Wlds[8 * WC];
  __shared__ float zpart[8 * 8 * 64];

  const int tid = threadIdx.x;
  const int w   = blockIdx.x;
  const int kq  = tid >> 6;
  const int b   = tid & 63;
  const int n0  = ((w & 7) << 6) + ((w >> 3) << 1);

#pragma unroll
  for (int i = 0; i < WC / 256; ++i) {
    const int idx4 = tid + (i << 9);
    const int rr   = idx4 / (WC / 4);
    const int col  = (idx4 % (WC / 4)) * 4;
    const int g = rr >> 1, u = rr & 1;
    const float* Wrow =
        ((g == 0) ? Wf : (g == 1) ? Wi : (g == 2) ? Wo : Wc) +
        (size_t)(n0 + u) * 1024;
    *(float4*)&Wlds[rr * WC + col] = *(const float4*)&Wrow[col];
  }

  float biasv[4] = {0.f, 0.f, 0.f, 0.f};
  float c_r = 0.f, h_r = 0.f;
  if (tid < 128) {
    const int u = tid >> 6;
    biasv[0] = bf[n0 + u]; biasv[1] = bi[n0 + u];
    biasv[2] = bo[n0 + u]; biasv[3] = bc[n0 + u];
  }
  __syncthreads();

  for (int t = 0; t < T_STEPS; ++t) {
    float zpre[4] = {0.f, 0.f, 0.f, 0.f};
    float mval = 0.f;
    if (tid < 128) {
      const int bb = tid & 63;
      mval = mask[t * 64 + bb];
#pragma unroll
      for (int g = 0; g < 4; ++g) zpre[g] = biasv[g];
    }

    float acc[8];
#pragma unroll
    for (int rr = 0; rr < 8; ++rr) acc[rr] = 0.f;

    {
      const float* hcur = hT + ((t & 1) << 15);
      const int k0 = kq << 6;
#pragma unroll
      for (int k4 = 0; k4 < 16; ++k4) {
        const int k = k0 + (k4 << 2);
        const float h0 = hcur[(k + 0) * 64 + b];
        const float h1 = hcur[(k + 1) * 64 + b];
        const float h2 = hcur[(k + 2) * 64 + b];
        const float h3 = hcur[(k + 3) * 64 + b];
#pragma unroll
        for (int rr = 0; rr < 8; ++rr) {
          float4 wv = *(const float4*)&Wlds[rr * WC + k];
          acc[rr] = fmaf(h0, wv.x, acc[rr]);
          acc[rr] = fmaf(h1, wv.y, acc[rr]);
          acc[rr] = fmaf(h2, wv.z, acc[rr]);
          acc[rr] = fmaf(h3, wv.w, acc[rr]);
        }
      }
    }
    {
      const float* xt = x + (size_t)t * (64 * 512) + b * 512;
      const int k0 = kq << 6;
#pragma unroll
      for (int k4 = 0; k4 < 16; ++k4) {
        const int k = k0 + (k4 << 2);
        float4 xv = *(const float4*)&xt[k];
#pragma unroll
        for (int rr = 0; rr < 8; ++rr) {
          float4 wv = *(const float4*)&Wlds[rr * WC + 512 + k];
          acc[rr] = fmaf(xv.x, wv.x, acc[rr]);
          acc[rr] = fmaf(xv.y, wv.y, acc[rr]);
          acc[rr] = fmaf(xv.z, wv.z, acc[rr]);
          acc[rr] = fmaf(xv.w, wv.w, acc[rr]);
        }
      }
    }

#pragma unroll
    for (int rr = 0; rr < 8; ++rr)
      zpart[((kq << 3) + rr) * 64 + b] = acc[rr];
    __syncthreads();

    if (tid < 128) {
      const int u = tid >> 6, bb = tid & 63;
      float z[4];
#pragma unroll
      for (int g = 0; g < 4; ++g) {
        const int rr = g * 2 + u;
        float s = zpre[g];
#pragma unroll
        for (int q = 0; q < 8; ++q) s += zpart[((q << 3) + rr) * 64 + bb];
        z[g] = s;
      }
      const float f  = sigf(z[0]);
      const float ig = sigf(z[1]);
      const float o  = sigf(z[2]);
      const float ct = tanhf_(z[3]);
      float cn = f * c_r + ig * ct;
      cn = mval * cn + (1.f - mval) * c_r;
      c_r = cn;
      float hn = o * tanhf_(cn);
      hn = mval * hn + (1.f - mval) * h_r;
      h_r = hn;
      const int n = n0 + u;
      hT[(((t + 1) & 1) << 15) + n * 64 + bb] = hn;
      out[((size_t)t * 64 + bb) * 512 + n]         = hn;
      out[HHIST + ((size_t)t * 64 + bb) * 512 + n] = ig;
    }

    if (t != T_STEPS - 1) grid_barrier(cnt, w, tid, t);
  }
}

// ---------------------------------------------------------------------------
// launch
// ---------------------------------------------------------------------------
extern "C" void kernel_launch(void* const* d_in, const int* in_sizes, int n_in,
                              void* d_out, int out_size, void* d_ws, size_t ws_size,
                              hipStream_t stream) {
  (void)in_sizes; (void)n_in; (void)out_size;
  // setup_inputs order: x, mask, Wf, bf, Wi, bi, Wc, bc, Wo, bo
  const float* x    = (const float*)d_in[0];
  const float* mask = (const float*)d_in[1];
  const float* Wf   = (const float*)d_in[2];
  const float* bf   = (const float*)d_in[3];
  const float* Wi   = (const float*)d_in[4];
  const float* bi   = (const float*)d_in[5];
  const float* Wc   = (const float*)d_in[6];
  const float* bc   = (const float*)d_in[7];
  const float* Wo   = (const float*)d_in[8];
  const float* bo   = (const float*)d_in[9];
  float* out = (float*)d_out;

  const size_t zx_bytes  = (size_t)T_STEPS * NROW * 64 * 4;   // 256 MiB
  const size_t h_bytes   = 2 * 8 * 512 * 8 * 4;               // 256 KiB
  const size_t flg_bytes = 4096;
  const bool fast = ws_size >= zx_bytes + h_bytes + flg_bytes;

  float* Zx; float* hT;
  if (fast) {
    Zx = (float*)d_ws;
    hT = (float*)((char*)d_ws + zx_bytes);
  } else {
    Zx = nullptr;
    hT = (float*)d_ws;
  }
  unsigned* flags = (unsigned*)((char*)hT + h_bytes);

  // zero h double-buffer + flags/counters every launch (graph replays!)
  hipMemsetAsync(hT, 0, h_bytes + flg_bytes, stream);

  if (fast) {
    hipLaunchKernelGGL(xgemm_kernel, dim3(16, 512), dim3(256), 0, stream,
                       x, Wf, Wi, Wo, Wc, bf, bi, bo, bc, Zx);
    void* kargs[] = { (void*)&mask, (void*)&Wf, (void*)&Wi, (void*)&Wo,
                      (void*)&Wc, (void*)&Zx, (void*)&hT, (void*)&flags,
                      (void*)&out };
    hipLaunchCooperativeKernel(reinterpret_cast<void*>(&lstm_rec_fast),
                               dim3(256), dim3(512), kargs, 0, stream);
  } else {
    void* kargs[] = { (void*)&x, (void*)&mask, (void*)&Wf, (void*)&Wi,
                      (void*)&Wo, (void*)&Wc, (void*)&bf, (void*)&bi,
                      (void*)&bo, (void*)&bc, (void*)&hT, (void*)&flags,
                      (void*)&out };
    hipLaunchCooperativeKernel(reinterpret_cast<void*>(&lstm_rec_inline),
                               dim3(256), dim3(512), kargs, 0, stream);
  }
}

// Round 6
// 4346.127 us; speedup vs baseline: 2.2447x; 1.8394x over previous
//
#include <hip/hip_runtime.h>
#include <math.h>

// Problem constants (fixed by the reference)
#define T_STEPS 512
#define BATCH   64
#define HID     512
#define NROW    2048          // 4*HID rows of concatenated W
#define HHIST   16777216ULL   // T*B*H floats (offset of i_hist in d_out)

// ---------------------------------------------------------------------------
// activation helpers (fp32, clamped to avoid exp overflow)
// ---------------------------------------------------------------------------
__device__ __forceinline__ float sigf(float z) {
  z = fminf(fmaxf(z, -30.f), 30.f);
  return 1.f / (1.f + __expf(-z));
}
__device__ __forceinline__ float tanhf_(float v) {
  v = fminf(fmaxf(v, -15.f), 15.f);
  const float e = __expf(2.f * v);
  return (e - 1.f) / (e + 1.f);
}

// ---------------------------------------------------------------------------
// Kernel A: Zx[t][g][r][b8] = b[r] + sum_k Wx[r][k] * x[t][g*8+b8][k]
// Layout [t][batch-group g][2048 rows][8 b]: each lstm group reads dense,
// single-XCD cache lines.
// ---------------------------------------------------------------------------
__global__ __launch_bounds__(256) void xgemm_kernel(
    const float* __restrict__ x,
    const float* __restrict__ Wf, const float* __restrict__ Wi,
    const float* __restrict__ Wo, const float* __restrict__ Wc,
    const float* __restrict__ bf, const float* __restrict__ bi,
    const float* __restrict__ bo, const float* __restrict__ bc,
    float* __restrict__ Zx)
{
  const int rtile = blockIdx.x;   // 0..15
  const int t     = blockIdx.y;   // 0..511
  const int g  = rtile >> 2;
  const int n0 = (rtile & 3) * 128;
  const float* Wg = (g == 0) ? Wf : (g == 1) ? Wi : (g == 2) ? Wo : Wc;
  const float* bg = (g == 0) ? bf : (g == 1) ? bi : (g == 2) ? bo : bc;

  __shared__ float Wt[32][132];   // [k][r] transposed, padded
  __shared__ float Xt[32][68];    // [k][b] transposed, padded

  const int tid = threadIdx.x;
  const int tr  = tid & 31;       // 4 r-rows each
  const int tb  = tid >> 5;       // 8 b-cols each (= batch group tb)

  float acc[4][8];
#pragma unroll
  for (int i = 0; i < 4; ++i)
#pragma unroll
    for (int j = 0; j < 8; ++j) acc[i][j] = 0.f;

  float biasv[4];
#pragma unroll
  for (int i = 0; i < 4; ++i) biasv[i] = bg[n0 + tr * 4 + i];

  const float* xt = x + (size_t)t * (BATCH * 512);

  for (int kc = 0; kc < 512; kc += 32) {
#pragma unroll
    for (int p = 0; p < 4; ++p) {
      const int r  = p * 32 + (tid >> 3);
      const int kk = (tid & 7) * 4;
      float4 v = *(const float4*)&Wg[(size_t)(n0 + r) * 1024 + 512 + kc + kk];
      Wt[kk + 0][r] = v.x; Wt[kk + 1][r] = v.y;
      Wt[kk + 2][r] = v.z; Wt[kk + 3][r] = v.w;
    }
    {
      const int b  = tid >> 2;
      const int kk = (tid & 3) * 8;
      float4 v0 = *(const float4*)&xt[b * 512 + kc + kk];
      float4 v1 = *(const float4*)&xt[b * 512 + kc + kk + 4];
      Xt[kk + 0][b] = v0.x; Xt[kk + 1][b] = v0.y;
      Xt[kk + 2][b] = v0.z; Xt[kk + 3][b] = v0.w;
      Xt[kk + 4][b] = v1.x; Xt[kk + 5][b] = v1.y;
      Xt[kk + 6][b] = v1.z; Xt[kk + 7][b] = v1.w;
    }
    __syncthreads();
#pragma unroll
    for (int kk = 0; kk < 32; ++kk) {
      float4 wv = *(const float4*)&Wt[kk][tr * 4];
      float4 x0 = *(const float4*)&Xt[kk][tb * 8];
      float4 x1 = *(const float4*)&Xt[kk][tb * 8 + 4];
      const float wa[4] = {wv.x, wv.y, wv.z, wv.w};
      const float xa[8] = {x0.x, x0.y, x0.z, x0.w, x1.x, x1.y, x1.z, x1.w};
#pragma unroll
      for (int i = 0; i < 4; ++i)
#pragma unroll
        for (int j = 0; j < 8; ++j)
          acc[i][j] = fmaf(wa[i], xa[j], acc[i][j]);
    }
    __syncthreads();
  }

  const int rg = g * 512 + n0 + tr * 4;
#pragma unroll
  for (int ir = 0; ir < 4; ++ir) {
    const float bv = biasv[ir];
    float4 o0 = make_float4(acc[ir][0] + bv, acc[ir][1] + bv,
                            acc[ir][2] + bv, acc[ir][3] + bv);
    float4 o1 = make_float4(acc[ir][4] + bv, acc[ir][5] + bv,
                            acc[ir][6] + bv, acc[ir][7] + bv);
    // [t][g=tb][row][8b] layout
    float* dst = Zx + (((size_t)t * 8 + tb) * NROW + rg + ir) * 8;
    *(float4*)dst       = o0;
    *(float4*)(dst + 4) = o1;
  }
}

// ---------------------------------------------------------------------------
// Kernel B (fast): 8 independent batch-groups of 32 wgs; NO grid barrier and
// (new this round) NO agent release/acquire anywhere in the step loop.
// Ordering protocol (AITER-style, vmcnt-based):
//   producer: h stores are sc1 write-through (relaxed agent atomics) ->
//   s_waitcnt vmcnt(0) + __syncthreads (ack'd at MALL = globally visible) ->
//   RELAXED flag increment (also sc1, reaches MALL after h).
//   consumer: RELAXED sc1 poll; sc1 data loads (bypass L1/L2, read MALL).
// No buffer_wbl2 / buffer_inv is ever emitted in the loop.
// out stores are nontemporal and issued AFTER the flag publish so their HBM
// ack drains under the next step's poll instead of the serial chain.
// ---------------------------------------------------------------------------
__global__ __launch_bounds__(512, 2) void lstm_rec_fast(
    const float* __restrict__ mask,
    const float* __restrict__ Wf, const float* __restrict__ Wi,
    const float* __restrict__ Wo, const float* __restrict__ Wc,
    const float* __restrict__ Zx,
    float* __restrict__ hT, unsigned* __restrict__ flags,
    float* __restrict__ out)
{
  __shared__ float hlds[4096];   // 1024 b128 slots (swizzled), 16 KB

  const int tid  = threadIdx.x;
  const int w    = blockIdx.x;        // 0..255
  const int g    = w & 7;             // batch group
  const int ib   = w >> 3;            // unit block 0..31
  const int wv   = tid >> 6;          // wave 0..7
  const int lane = tid & 63;

  const int unit0 = ib * 16 + wv * 2; // this wave's two units
  // lane's final output index after reduce-scatter: lane = r_local*8 + b
  const int g4l = lane >> 4;          // gate 0..3 (f,i,o,c)
  const int u2l = (lane >> 3) & 1;    // unit parity
  const int bl  = lane & 7;           // batch within group

  // ---- W preload into registers: Wreg[r][j] = Wgate[g4][unit0+u2][8*lane+j]
  float Wreg[8][8];
  {
    const float* Wm[4] = {Wf, Wi, Wo, Wc};
#pragma unroll
    for (int g4 = 0; g4 < 4; ++g4)
#pragma unroll
      for (int u2 = 0; u2 < 2; ++u2) {
        const float* row = Wm[g4] + (size_t)(unit0 + u2) * 1024 + lane * 8;
        float4 a = *(const float4*)row;
        float4 b = *(const float4*)(row + 4);
        float* Wr = Wreg[g4 * 2 + u2];
        Wr[0] = a.x; Wr[1] = a.y; Wr[2] = a.z; Wr[3] = a.w;
        Wr[4] = b.x; Wr[5] = b.y; Wr[6] = b.z; Wr[7] = b.w;
      }
  }

  float c_r = 0.f, h_r = 0.f;          // live in lanes 0..15 only
  const int base16 = lane << 4;        // 16*lane (LDS slot base)

  for (int t = 0; t < T_STEPS; ++t) {
    // ---- issue x-part + mask loads early (plain cached; consumed after dot)
    const float zpre = Zx[(((size_t)t * 8 + g) * NROW +
                           g4l * 512 + unit0 + u2l) * 8 + bl];
    const float mval = mask[t * 64 + g * 8 + bl];

    // ---- wait for all 32 producers of this group to publish h^t
    if (t > 0 && wv == 0) {
      const unsigned tgt = (unsigned)t;
      const unsigned fidx = (unsigned)(g + 8 * (lane & 31));
      while (true) {
        unsigned f = __hip_atomic_load(&flags[fidx], __ATOMIC_RELAXED,
                                       __HIP_MEMORY_SCOPE_AGENT);
        if (__all((lane >= 32) | (f >= tgt))) break;
        __builtin_amdgcn_s_sleep(1);
      }
    }
    __syncthreads();   // also fences step t-1's hlds reads vs re-stage below

    // ---- stage h^t (group slice, 512 k x 8 b) into LDS, sc1 (MALL) loads.
    // thread tid handles k = tid; slot s = 2k+half, phys = (s&~7)|((s+(s>>4))&7)
    {
      const int buf = t & 1;
      const unsigned long long* hq =
          (const unsigned long long*)hT + ((size_t)(buf * 8 + g) * 512 + tid) * 4;
      unsigned long long q0 = __hip_atomic_load(hq + 0, __ATOMIC_RELAXED,
                                                __HIP_MEMORY_SCOPE_AGENT);
      unsigned long long q1 = __hip_atomic_load(hq + 1, __ATOMIC_RELAXED,
                                                __HIP_MEMORY_SCOPE_AGENT);
      unsigned long long q2 = __hip_atomic_load(hq + 2, __ATOMIC_RELAXED,
                                                __HIP_MEMORY_SCOPE_AGENT);
      unsigned long long q3 = __hip_atomic_load(hq + 3, __ATOMIC_RELAXED,
                                                __HIP_MEMORY_SCOPE_AGENT);
      float4 lo = make_float4(__uint_as_float((unsigned)q0),
                              __uint_as_float((unsigned)(q0 >> 32)),
                              __uint_as_float((unsigned)q1),
                              __uint_as_float((unsigned)(q1 >> 32)));
      float4 hi = make_float4(__uint_as_float((unsigned)q2),
                              __uint_as_float((unsigned)(q2 >> 32)),
                              __uint_as_float((unsigned)q3),
                              __uint_as_float((unsigned)(q3 >> 32)));
      const int s0 = tid * 2, s1 = s0 + 1;
      const int p0 = (s0 & ~7) | ((s0 + (s0 >> 4)) & 7);
      const int p1 = (s1 & ~7) | ((s1 + (s1 >> 4)) & 7);
      *(float4*)&hlds[p0 * 4] = lo;
      *(float4*)&hlds[p1 * 4] = hi;
    }
    __syncthreads();

    // ---- dot: v[r*8+b] = sum over lane's 8 k of Wreg[r][j] * h[k][b]
    float v[64];
#pragma unroll
    for (int q = 0; q < 64; ++q) v[q] = 0.f;

#pragma unroll
    for (int j = 0; j < 8; ++j) {
      const int s0 = base16 + 2 * j, s1 = s0 + 1;
      const int p0 = (s0 & ~7) | ((s0 + lane) & 7);   // s>>4 == lane here
      const int p1 = (s1 & ~7) | ((s1 + lane) & 7);
      const float4 h0 = *(const float4*)&hlds[p0 * 4]; // h[k][0..3]
      const float4 h1 = *(const float4*)&hlds[p1 * 4]; // h[k][4..7]
#pragma unroll
      for (int r = 0; r < 8; ++r) {
        const float wr = Wreg[r][j];
        v[r * 8 + 0] = fmaf(wr, h0.x, v[r * 8 + 0]);
        v[r * 8 + 1] = fmaf(wr, h0.y, v[r * 8 + 1]);
        v[r * 8 + 2] = fmaf(wr, h0.z, v[r * 8 + 2]);
        v[r * 8 + 3] = fmaf(wr, h0.w, v[r * 8 + 3]);
        v[r * 8 + 4] = fmaf(wr, h1.x, v[r * 8 + 4]);
        v[r * 8 + 5] = fmaf(wr, h1.y, v[r * 8 + 5]);
        v[r * 8 + 6] = fmaf(wr, h1.z, v[r * 8 + 6]);
        v[r * 8 + 7] = fmaf(wr, h1.w, v[r * 8 + 7]);
      }
    }

    // ---- in-wave reduce-scatter over 64 lanes: lane l ends with z[index l].
    // Recursive halving: KEEP your own half, SEND the complementary half.
#pragma unroll
    for (int m = 0; m < 6; ++m) {
      const int lb = (lane >> m) & 1;
#pragma unroll
      for (int p = 0; p < (32 >> m); ++p) {
        const float keep = lb ? v[2 * p + 1] : v[2 * p];
        const float send = lb ? v[2 * p]     : v[2 * p + 1];
        v[p] = keep + __shfl_xor(send, 1 << m, 64);
      }
    }
    const float z = v[0] + zpre;

    // gather the 4 gate z's of (u2l, bl) to lanes 0..15
    const float zi_ = __shfl(z, lane + 16, 64);
    const float zo_ = __shfl(z, lane + 32, 64);
    const float zc_ = __shfl(z, lane + 48, 64);

    const float f  = sigf(z);      // lanes 0..15: z is the f-gate z
    const float ig = sigf(zi_);
    const float o  = sigf(zo_);
    const float ct = tanhf_(zc_);
    float cn = f * c_r + ig * ct;
    cn = mval * cn + (1.f - mval) * c_r;
    float hn = o * tanhf_(cn);
    hn = mval * hn + (1.f - mval) * h_r;

    if (lane < 16) {
      c_r = cn; h_r = hn;
      const int n = unit0 + u2l;
      // write-through h for next step (sc1 -> MALL, the coherence point)
      const size_t hidx = ((size_t)(((t + 1) & 1) * 8 + g) * 512 + n) * 8 + bl;
      __hip_atomic_store((unsigned*)&hT[hidx], __float_as_uint(hn),
                         __ATOMIC_RELAXED, __HIP_MEMORY_SCOPE_AGENT);
    }

    if (t + 1 < T_STEPS) {
      // vmcnt(0): every wave's h store is ACK'd at MALL (globally visible)
      asm volatile("s_waitcnt vmcnt(0)" ::: "memory");
      __syncthreads();
      // RELAXED publish: no release fence -> no buffer_wbl2 in the loop.
      // Point-to-point order at MALL: h stores completed before this issues.
      if (tid == 0)
        __hip_atomic_fetch_add(&flags[w], 1u, __ATOMIC_RELAXED,
                               __HIP_MEMORY_SCOPE_AGENT);
    }

    // out stores AFTER the publish: their HBM ack drains under the next
    // step's poll instead of sitting on the flag chain. (out is never read
    // in-kernel; kernel-end release makes it visible to the harness.)
    if (lane < 16) {
      const int n = unit0 + u2l;
      const size_t ob = ((size_t)t * 64 + g * 8 + bl) * 512 + n;
      __builtin_nontemporal_store(hn, &out[ob]);
      __builtin_nontemporal_store(ig, &out[HHIST + ob]);
    }
  }
}

// ---------------------------------------------------------------------------
// Fallback (ws too small): round-3 inline-x cooperative version, verbatim.
// ---------------------------------------------------------------------------
__device__ __forceinline__ void grid_barrier(unsigned* cnt, int w, int tid, int round) {
  __syncthreads();
  if (tid == 0) {
    __builtin_amdgcn_fence(__ATOMIC_RELEASE, "agent");
    unsigned* gc = cnt + 16 + ((w >> 4) << 5);
    unsigned prev = __hip_atomic_fetch_add(gc, 1u, __ATOMIC_RELAXED,
                                           __HIP_MEMORY_SCOPE_AGENT);
    if ((prev & 15u) == 15u)
      __hip_atomic_fetch_add(cnt, 1u, __ATOMIC_RELAXED,
                             __HIP_MEMORY_SCOPE_AGENT);
    const unsigned target = (unsigned)(round + 1) * 16u;
    while (__hip_atomic_load(cnt, __ATOMIC_RELAXED,
                             __HIP_MEMORY_SCOPE_AGENT) < target)
      __builtin_amdgcn_s_sleep(2);
    __builtin_amdgcn_fence(__ATOMIC_ACQUIRE, "agent");
  }
  __syncthreads();
}

__global__ __launch_bounds__(512) void lstm_rec_inline(
    const float* __restrict__ x,  const float* __restrict__ mask,
    const float* __restrict__ Wf, const float* __restrict__ Wi,
    const float* __restrict__ Wo, const float* __restrict__ Wc,
    const float* __restrict__ bf, const float* __restrict__ bi,
    const float* __restrict__ bo, const float* __restrict__ bc,
    float* __restrict__ hT, unsigned* __restrict__ cnt,
    float* __restrict__ out)
{
  constexpr int WC = 1024;
  __shared__ float Wlds[8 * WC];
  __shared__ float zpart[8 * 8 * 64];

  const int tid = threadIdx.x;
  const int w   = blockIdx.x;
  const int kq  = tid >> 6;
  const int b   = tid & 63;
  const int n0  = ((w & 7) << 6) + ((w >> 3) << 1);

#pragma unroll
  for (int i = 0; i < WC / 256; ++i) {
    const int idx4 = tid + (i << 9);
    const int rr   = idx4 / (WC / 4);
    const int col  = (idx4 % (WC / 4)) * 4;
    const int g = rr >> 1, u = rr & 1;
    const float* Wrow =
        ((g == 0) ? Wf : (g == 1) ? Wi : (g == 2) ? Wo : Wc) +
        (size_t)(n0 + u) * 1024;
    *(float4*)&Wlds[rr * WC + col] = *(const float4*)&Wrow[col];
  }

  float biasv[4] = {0.f, 0.f, 0.f, 0.f};
  float c_r = 0.f, h_r = 0.f;
  if (tid < 128) {
    const int u = tid >> 6;
    biasv[0] = bf[n0 + u]; biasv[1] = bi[n0 + u];
    biasv[2] = bo[n0 + u]; biasv[3] = bc[n0 + u];
  }
  __syncthreads();

  for (int t = 0; t < T_STEPS; ++t) {
    float zpre[4] = {0.f, 0.f, 0.f, 0.f};
    float mval = 0.f;
    if (tid < 128) {
      const int bb = tid & 63;
      mval = mask[t * 64 + bb];
#pragma unroll
      for (int g = 0; g < 4; ++g) zpre[g] = biasv[g];
    }

    float acc[8];
#pragma unroll
    for (int rr = 0; rr < 8; ++rr) acc[rr] = 0.f;

    {
      const float* hcur = hT + ((t & 1) << 15);
      const int k0 = kq << 6;
#pragma unroll
      for (int k4 = 0; k4 < 16; ++k4) {
        const int k = k0 + (k4 << 2);
        const float h0 = hcur[(k + 0) * 64 + b];
        const float h1 = hcur[(k + 1) * 64 + b];
        const float h2 = hcur[(k + 2) * 64 + b];
        const float h3 = hcur[(k + 3) * 64 + b];
#pragma unroll
        for (int rr = 0; rr < 8; ++rr) {
          float4 wv = *(const float4*)&Wlds[rr * WC + k];
          acc[rr] = fmaf(h0, wv.x, acc[rr]);
          acc[rr] = fmaf(h1, wv.y, acc[rr]);
          acc[rr] = fmaf(h2, wv.z, acc[rr]);
          acc[rr] = fmaf(h3, wv.w, acc[rr]);
        }
      }
    }
    {
      const float* xt = x + (size_t)t * (64 * 512) + b * 512;
      const int k0 = kq << 6;
#pragma unroll
      for (int k4 = 0; k4 < 16; ++k4) {
        const int k = k0 + (k4 << 2);
        float4 xv = *(const float4*)&xt[k];
#pragma unroll
        for (int rr = 0; rr < 8; ++rr) {
          float4 wv = *(const float4*)&Wlds[rr * WC + 512 + k];
          acc[rr] = fmaf(xv.x, wv.x, acc[rr]);
          acc[rr] = fmaf(xv.y, wv.y, acc[rr]);
          acc[rr] = fmaf(xv.z, wv.z, acc[rr]);
          acc[rr] = fmaf(xv.w, wv.w, acc[rr]);
        }
      }
    }

#pragma unroll
    for (int rr = 0; rr < 8; ++rr)
      zpart[((kq << 3) + rr) * 64 + b] = acc[rr];
    __syncthreads();

    if (tid < 128) {
      const int u = tid >> 6, bb = tid & 63;
      float z[4];
#pragma unroll
      for (int g = 0; g < 4; ++g) {
        const int rr = g * 2 + u;
        float s = zpre[g];
#pragma unroll
        for (int q = 0; q < 8; ++q) s += zpart[((q << 3) + rr) * 64 + bb];
        z[g] = s;
      }
      const float f  = sigf(z[0]);
      const float ig = sigf(z[1]);
      const float o  = sigf(z[2]);
      const float ct = tanhf_(z[3]);
      float cn = f * c_r + ig * ct;
      cn = mval * cn + (1.f - mval) * c_r;
      c_r = cn;
      float hn = o * tanhf_(cn);
      hn = mval * hn + (1.f - mval) * h_r;
      h_r = hn;
      const int n = n0 + u;
      hT[(((t + 1) & 1) << 15) + n * 64 + bb] = hn;
      out[((size_t)t * 64 + bb) * 512 + n]         = hn;
      out[HHIST + ((size_t)t * 64 + bb) * 512 + n] = ig;
    }

    if (t != T_STEPS - 1) grid_barrier(cnt, w, tid, t);
  }
}

// ---------------------------------------------------------------------------
// launch
// ---------------------------------------------------------------------------
extern "C" void kernel_launch(void* const* d_in, const int* in_sizes, int n_in,
                              void* d_out, int out_size, void* d_ws, size_t ws_size,
                              hipStream_t stream) {
  (void)in_sizes; (void)n_in; (void)out_size;
  // setup_inputs order: x, mask, Wf, bf, Wi, bi, Wc, bc, Wo, bo
  const float* x    = (const float*)d_in[0];
  const float* mask = (const float*)d_in[1];
  const float* Wf   = (const float*)d_in[2];
  const float* bf   = (const float*)d_in[3];
  const float* Wi   = (const float*)d_in[4];
  const float* bi   = (const float*)d_in[5];
  const float* Wc   = (const float*)d_in[6];
  const float* bc   = (const float*)d_in[7];
  const float* Wo   = (const float*)d_in[8];
  const float* bo   = (const float*)d_in[9];
  float* out = (float*)d_out;

  const size_t zx_bytes  = (size_t)T_STEPS * NROW * 64 * 4;   // 256 MiB
  const size_t h_bytes   = 2 * 8 * 512 * 8 * 4;               // 256 KiB
  const size_t flg_bytes = 4096;
  const bool fast = ws_size >= zx_bytes + h_bytes + flg_bytes;

  float* Zx; float* hT;
  if (fast) {
    Zx = (float*)d_ws;
    hT = (float*)((char*)d_ws + zx_bytes);
  } else {
    Zx = nullptr;
    hT = (float*)d_ws;
  }
  unsigned* flags = (unsigned*)((char*)hT + h_bytes);

  // zero h double-buffer + flags/counters every launch (graph replays!)
  hipMemsetAsync(hT, 0, h_bytes + flg_bytes, stream);

  if (fast) {
    hipLaunchKernelGGL(xgemm_kernel, dim3(16, 512), dim3(256), 0, stream,
                       x, Wf, Wi, Wo, Wc, bf, bi, bo, bc, Zx);
    void* kargs[] = { (void*)&mask, (void*)&Wf, (void*)&Wi, (void*)&Wo,
                      (void*)&Wc, (void*)&Zx, (void*)&hT, (void*)&flags,
                      (void*)&out };
    hipLaunchCooperativeKernel(reinterpret_cast<void*>(&lstm_rec_fast),
                               dim3(256), dim3(512), kargs, 0, stream);
  } else {
    void* kargs[] = { (void*)&x, (void*)&mask, (void*)&Wf, (void*)&Wi,
                      (void*)&Wo, (void*)&Wc, (void*)&bf, (void*)&bi,
                      (void*)&bo, (void*)&bc, (void*)&hT, (void*)&flags,
                      (void*)&out };
    hipLaunchCooperativeKernel(reinterpret_cast<void*>(&lstm_rec_inline),
                               dim3(256), dim3(512), kargs, 0, stream);
  }
}

// Round 7
// 3781.941 us; speedup vs baseline: 2.5796x; 1.1492x over previous
//
#include <hip/hip_runtime.h>
#include <math.h>

// Problem constants (fixed by the reference)
#define T_STEPS 512
#define BATCH   64
#define HID     512
#define NROW    2048          // 4*HID rows of concatenated W
#define HHIST   16777216ULL   // T*B*H floats (offset of i_hist in d_out)

// ---------------------------------------------------------------------------
// activation helpers (fp32, clamped to avoid exp overflow)
// ---------------------------------------------------------------------------
__device__ __forceinline__ float sigf(float z) {
  z = fminf(fmaxf(z, -30.f), 30.f);
  return 1.f / (1.f + __expf(-z));
}
__device__ __forceinline__ float tanhf_(float v) {
  v = fminf(fmaxf(v, -15.f), 15.f);
  const float e = __expf(2.f * v);
  return (e - 1.f) / (e + 1.f);
}

// ---------------------------------------------------------------------------
// Kernel A: Zx[t][g][r][b8] = b[r] + sum_k Wx[r][k] * x[t][g*8+b8][k]
// Layout [t][batch-group g][2048 rows][8 b]: each lstm group reads dense,
// single-XCD cache lines.  (unchanged)
// ---------------------------------------------------------------------------
__global__ __launch_bounds__(256) void xgemm_kernel(
    const float* __restrict__ x,
    const float* __restrict__ Wf, const float* __restrict__ Wi,
    const float* __restrict__ Wo, const float* __restrict__ Wc,
    const float* __restrict__ bf, const float* __restrict__ bi,
    const float* __restrict__ bo, const float* __restrict__ bc,
    float* __restrict__ Zx)
{
  const int rtile = blockIdx.x;   // 0..15
  const int t     = blockIdx.y;   // 0..511
  const int g  = rtile >> 2;
  const int n0 = (rtile & 3) * 128;
  const float* Wg = (g == 0) ? Wf : (g == 1) ? Wi : (g == 2) ? Wo : Wc;
  const float* bg = (g == 0) ? bf : (g == 1) ? bi : (g == 2) ? bo : bc;

  __shared__ float Wt[32][132];   // [k][r] transposed, padded
  __shared__ float Xt[32][68];    // [k][b] transposed, padded

  const int tid = threadIdx.x;
  const int tr  = tid & 31;       // 4 r-rows each
  const int tb  = tid >> 5;       // 8 b-cols each (= batch group tb)

  float acc[4][8];
#pragma unroll
  for (int i = 0; i < 4; ++i)
#pragma unroll
    for (int j = 0; j < 8; ++j) acc[i][j] = 0.f;

  float biasv[4];
#pragma unroll
  for (int i = 0; i < 4; ++i) biasv[i] = bg[n0 + tr * 4 + i];

  const float* xt = x + (size_t)t * (BATCH * 512);

  for (int kc = 0; kc < 512; kc += 32) {
#pragma unroll
    for (int p = 0; p < 4; ++p) {
      const int r  = p * 32 + (tid >> 3);
      const int kk = (tid & 7) * 4;
      float4 v = *(const float4*)&Wg[(size_t)(n0 + r) * 1024 + 512 + kc + kk];
      Wt[kk + 0][r] = v.x; Wt[kk + 1][r] = v.y;
      Wt[kk + 2][r] = v.z; Wt[kk + 3][r] = v.w;
    }
    {
      const int b  = tid >> 2;
      const int kk = (tid & 3) * 8;
      float4 v0 = *(const float4*)&xt[b * 512 + kc + kk];
      float4 v1 = *(const float4*)&xt[b * 512 + kc + kk + 4];
      Xt[kk + 0][b] = v0.x; Xt[kk + 1][b] = v0.y;
      Xt[kk + 2][b] = v0.z; Xt[kk + 3][b] = v0.w;
      Xt[kk + 4][b] = v1.x; Xt[kk + 5][b] = v1.y;
      Xt[kk + 6][b] = v1.z; Xt[kk + 7][b] = v1.w;
    }
    __syncthreads();
#pragma unroll
    for (int kk = 0; kk < 32; ++kk) {
      float4 wv = *(const float4*)&Wt[kk][tr * 4];
      float4 x0 = *(const float4*)&Xt[kk][tb * 8];
      float4 x1 = *(const float4*)&Xt[kk][tb * 8 + 4];
      const float wa[4] = {wv.x, wv.y, wv.z, wv.w};
      const float xa[8] = {x0.x, x0.y, x0.z, x0.w, x1.x, x1.y, x1.z, x1.w};
#pragma unroll
      for (int i = 0; i < 4; ++i)
#pragma unroll
        for (int j = 0; j < 8; ++j)
          acc[i][j] = fmaf(wa[i], xa[j], acc[i][j]);
    }
    __syncthreads();
  }

  const int rg = g * 512 + n0 + tr * 4;
#pragma unroll
  for (int ir = 0; ir < 4; ++ir) {
    const float bv = biasv[ir];
    float4 o0 = make_float4(acc[ir][0] + bv, acc[ir][1] + bv,
                            acc[ir][2] + bv, acc[ir][3] + bv);
    float4 o1 = make_float4(acc[ir][4] + bv, acc[ir][5] + bv,
                            acc[ir][6] + bv, acc[ir][7] + bv);
    // [t][g=tb][row][8b] layout
    float* dst = Zx + (((size_t)t * 8 + tb) * NROW + rg + ir) * 8;
    *(float4*)dst       = o0;
    *(float4*)(dst + 4) = o1;
  }
}

// ---------------------------------------------------------------------------
// Kernel B (fast): 8 independent batch-groups of 32 wgs. NO grid barrier,
// NO flags, NO fences, NO vmcnt stalls in the loop.
// h exchange is EPOCH-TAGGED: each h value is an atomic b64 pair
// (epoch<<32 | fp32bits), sc1 write-through to MALL. Consumers load their
// pairs directly and retry until epoch==t — the whole producer->consumer
// path is ONE MALL round trip after the data lands.
// Safety: double buffer (t&1) + the old invariant (producer publishing
// epoch t+1 into buf[(t+1)&1] implies all wgs finished reading epoch t-1
// from it); epoch check turns any stale interleaving into a retry.
// Deadlock-free: producers never wait on consumers.
// ---------------------------------------------------------------------------
__global__ __launch_bounds__(512, 2) void lstm_rec_fast(
    const float* __restrict__ mask,
    const float* __restrict__ Wf, const float* __restrict__ Wi,
    const float* __restrict__ Wo, const float* __restrict__ Wc,
    const float* __restrict__ Zx,
    unsigned long long* __restrict__ hP,   // [2][8][512][8] (epoch,val) pairs
    float* __restrict__ out)
{
  __shared__ float hlds[4096];   // 1024 b128 slots (swizzled), 16 KB

  const int tid  = threadIdx.x;
  const int w    = blockIdx.x;        // 0..255
  const int g    = w & 7;             // batch group
  const int ib   = w >> 3;            // unit block 0..31
  const int wv   = tid >> 6;          // wave 0..7
  const int lane = tid & 63;

  const int unit0 = ib * 16 + wv * 2; // this wave's two units
  // lane's final output index after reduce-scatter: lane = r_local*8 + b
  const int g4l = lane >> 4;          // gate 0..3 (f,i,o,c)
  const int u2l = (lane >> 3) & 1;    // unit parity
  const int bl  = lane & 7;           // batch within group

  // ---- W preload into registers: Wreg[r][j] = Wgate[g4][unit0+u2][8*lane+j]
  float Wreg[8][8];
  {
    const float* Wm[4] = {Wf, Wi, Wo, Wc};
#pragma unroll
    for (int g4 = 0; g4 < 4; ++g4)
#pragma unroll
      for (int u2 = 0; u2 < 2; ++u2) {
        const float* row = Wm[g4] + (size_t)(unit0 + u2) * 1024 + lane * 8;
        float4 a = *(const float4*)row;
        float4 b = *(const float4*)(row + 4);
        float* Wr = Wreg[g4 * 2 + u2];
        Wr[0] = a.x; Wr[1] = a.y; Wr[2] = a.z; Wr[3] = a.w;
        Wr[4] = b.x; Wr[5] = b.y; Wr[6] = b.z; Wr[7] = b.w;
      }
  }

  float c_r = 0.f, h_r = 0.f;          // live in lanes 0..15 only
  const int base16 = lane << 4;        // 16*lane (LDS slot base)

  for (int t = 0; t < T_STEPS; ++t) {
    // ---- issue x-part + mask loads early (plain cached; consumed after dot)
    const float zpre = Zx[(((size_t)t * 8 + g) * NROW +
                           g4l * 512 + unit0 + u2l) * 8 + bl];
    const float mval = mask[t * 64 + g * 8 + bl];

    __syncthreads();   // step t-1's hlds reads done (all waves) before restage

    // ---- stage h^t: thread tid owns k=tid; 8 (epoch,val) pairs, retry
    // until all epochs == t. Slot s = 2k+half, phys = (s&~7)|((s+(s>>4))&7).
    {
      unsigned long long* hq =
          hP + ((size_t)((t & 1) * 8 + g) * 512 + tid) * 8;
      unsigned long long q[8];
      while (true) {
#pragma unroll
        for (int j = 0; j < 8; ++j)
          q[j] = __hip_atomic_load(hq + j, __ATOMIC_RELAXED,
                                   __HIP_MEMORY_SCOPE_AGENT);
        bool ok = true;
#pragma unroll
        for (int j = 0; j < 8; ++j)
          ok &= ((unsigned)(q[j] >> 32) == (unsigned)t);
        if (ok) break;
        __builtin_amdgcn_s_sleep(1);
      }
      float4 lo = make_float4(__uint_as_float((unsigned)q[0]),
                              __uint_as_float((unsigned)q[1]),
                              __uint_as_float((unsigned)q[2]),
                              __uint_as_float((unsigned)q[3]));
      float4 hi = make_float4(__uint_as_float((unsigned)q[4]),
                              __uint_as_float((unsigned)q[5]),
                              __uint_as_float((unsigned)q[6]),
                              __uint_as_float((unsigned)q[7]));
      const int s0 = tid * 2, s1 = s0 + 1;
      const int p0 = (s0 & ~7) | ((s0 + (s0 >> 4)) & 7);
      const int p1 = (s1 & ~7) | ((s1 + (s1 >> 4)) & 7);
      *(float4*)&hlds[p0 * 4] = lo;
      *(float4*)&hlds[p1 * 4] = hi;
    }
    __syncthreads();   // staging complete

    // ---- dot: v[r*8+b] = sum over lane's 8 k of Wreg[r][j] * h[k][b]
    float v[64];
    // j = 0 peeled: init accumulators with mul (no zero-init pass)
    {
      const int s0 = base16, s1 = s0 + 1;
      const int p0 = (s0 & ~7) | ((s0 + lane) & 7);   // s>>4 == lane here
      const int p1 = (s1 & ~7) | ((s1 + lane) & 7);
      const float4 h0 = *(const float4*)&hlds[p0 * 4];
      const float4 h1 = *(const float4*)&hlds[p1 * 4];
#pragma unroll
      for (int r = 0; r < 8; ++r) {
        const float wr = Wreg[r][0];
        v[r * 8 + 0] = wr * h0.x;  v[r * 8 + 1] = wr * h0.y;
        v[r * 8 + 2] = wr * h0.z;  v[r * 8 + 3] = wr * h0.w;
        v[r * 8 + 4] = wr * h1.x;  v[r * 8 + 5] = wr * h1.y;
        v[r * 8 + 6] = wr * h1.z;  v[r * 8 + 7] = wr * h1.w;
      }
    }
#pragma unroll
    for (int j = 1; j < 8; ++j) {
      const int s0 = base16 + 2 * j, s1 = s0 + 1;
      const int p0 = (s0 & ~7) | ((s0 + lane) & 7);
      const int p1 = (s1 & ~7) | ((s1 + lane) & 7);
      const float4 h0 = *(const float4*)&hlds[p0 * 4]; // h[k][0..3]
      const float4 h1 = *(const float4*)&hlds[p1 * 4]; // h[k][4..7]
#pragma unroll
      for (int r = 0; r < 8; ++r) {
        const float wr = Wreg[r][j];
        v[r * 8 + 0] = fmaf(wr, h0.x, v[r * 8 + 0]);
        v[r * 8 + 1] = fmaf(wr, h0.y, v[r * 8 + 1]);
        v[r * 8 + 2] = fmaf(wr, h0.z, v[r * 8 + 2]);
        v[r * 8 + 3] = fmaf(wr, h0.w, v[r * 8 + 3]);
        v[r * 8 + 4] = fmaf(wr, h1.x, v[r * 8 + 4]);
        v[r * 8 + 5] = fmaf(wr, h1.y, v[r * 8 + 5]);
        v[r * 8 + 6] = fmaf(wr, h1.z, v[r * 8 + 6]);
        v[r * 8 + 7] = fmaf(wr, h1.w, v[r * 8 + 7]);
      }
    }

    // ---- in-wave reduce-scatter over 64 lanes: lane l ends with z[index l].
    // Recursive halving: KEEP your own half, SEND the complementary half.
#pragma unroll
    for (int m = 0; m < 6; ++m) {
      const int lb = (lane >> m) & 1;
#pragma unroll
      for (int p = 0; p < (32 >> m); ++p) {
        const float keep = lb ? v[2 * p + 1] : v[2 * p];
        const float send = lb ? v[2 * p]     : v[2 * p + 1];
        v[p] = keep + __shfl_xor(send, 1 << m, 64);
      }
    }
    const float z = v[0] + zpre;

    // gather the 4 gate z's of (u2l, bl) to lanes 0..15
    const float zi_ = __shfl(z, lane + 16, 64);
    const float zo_ = __shfl(z, lane + 32, 64);
    const float zc_ = __shfl(z, lane + 48, 64);

    const float f  = sigf(z);      // lanes 0..15: z is the f-gate z
    const float ig = sigf(zi_);
    const float o  = sigf(zo_);
    const float ct = tanhf_(zc_);
    float cn = f * c_r + ig * ct;
    cn = mval * cn + (1.f - mval) * c_r;
    float hn = o * tanhf_(cn);
    hn = mval * hn + (1.f - mval) * h_r;

    if (lane < 16) {
      c_r = cn; h_r = hn;
      const int n = unit0 + u2l;
      // epoch-tagged publish: fire-and-forget b64 write-through to MALL
      const size_t hidx = ((size_t)(((t + 1) & 1) * 8 + g) * 512 + n) * 8 + bl;
      const unsigned long long pk =
          ((unsigned long long)(unsigned)(t + 1) << 32) |
          (unsigned long long)__float_as_uint(hn);
      __hip_atomic_store(hP + hidx, pk, __ATOMIC_RELAXED,
                         __HIP_MEMORY_SCOPE_AGENT);
      // history outputs: nontemporal, off the critical path
      const size_t ob = ((size_t)t * 64 + g * 8 + bl) * 512 + n;
      __builtin_nontemporal_store(hn, &out[ob]);
      __builtin_nontemporal_store(ig, &out[HHIST + ob]);
    }
  }
}

// ---------------------------------------------------------------------------
// Fallback (ws too small): round-3 inline-x cooperative version, verbatim.
// ---------------------------------------------------------------------------
__device__ __forceinline__ void grid_barrier(unsigned* cnt, int w, int tid, int round) {
  __syncthreads();
  if (tid == 0) {
    __builtin_amdgcn_fence(__ATOMIC_RELEASE, "agent");
    unsigned* gc = cnt + 16 + ((w >> 4) << 5);
    unsigned prev = __hip_atomic_fetch_add(gc, 1u, __ATOMIC_RELAXED,
                                           __HIP_MEMORY_SCOPE_AGENT);
    if ((prev & 15u) == 15u)
      __hip_atomic_fetch_add(cnt, 1u, __ATOMIC_RELAXED,
                             __HIP_MEMORY_SCOPE_AGENT);
    const unsigned target = (unsigned)(round + 1) * 16u;
    while (__hip_atomic_load(cnt, __ATOMIC_RELAXED,
                             __HIP_MEMORY_SCOPE_AGENT) < target)
      __builtin_amdgcn_s_sleep(2);
    __builtin_amdgcn_fence(__ATOMIC_ACQUIRE, "agent");
  }
  __syncthreads();
}

__global__ __launch_bounds__(512) void lstm_rec_inline(
    const float* __restrict__ x,  const float* __restrict__ mask,
    const float* __restrict__ Wf, const float* __restrict__ Wi,
    const float* __restrict__ Wo, const float* __restrict__ Wc,
    const float* __restrict__ bf, const float* __restrict__ bi,
    const float* __restrict__ bo, const float* __restrict__ bc,
    float* __restrict__ hT, unsigned* __restrict__ cnt,
    float* __restrict__ out)
{
  constexpr int WC = 1024;
  __shared__ float Wlds[8 * WC];
  __shared__ float zpart[8 * 8 * 64];

  const int tid = threadIdx.x;
  const int w   = blockIdx.x;
  const int kq  = tid >> 6;
  const int b   = tid & 63;
  const int n0  = ((w & 7) << 6) + ((w >> 3) << 1);

#pragma unroll
  for (int i = 0; i < WC / 256; ++i) {
    const int idx4 = tid + (i << 9);
    const int rr   = idx4 / (WC / 4);
    const int col  = (idx4 % (WC / 4)) * 4;
    const int g = rr >> 1, u = rr & 1;
    const float* Wrow =
        ((g == 0) ? Wf : (g == 1) ? Wi : (g == 2) ? Wo : Wc) +
        (size_t)(n0 + u) * 1024;
    *(float4*)&Wlds[rr * WC + col] = *(const float4*)&Wrow[col];
  }

  float biasv[4] = {0.f, 0.f, 0.f, 0.f};
  float c_r = 0.f, h_r = 0.f;
  if (tid < 128) {
    const int u = tid >> 6;
    biasv[0] = bf[n0 + u]; biasv[1] = bi[n0 + u];
    biasv[2] = bo[n0 + u]; biasv[3] = bc[n0 + u];
  }
  __syncthreads();

  for (int t = 0; t < T_STEPS; ++t) {
    float zpre[4] = {0.f, 0.f, 0.f, 0.f};
    float mval = 0.f;
    if (tid < 128) {
      const int bb = tid & 63;
      mval = mask[t * 64 + bb];
#pragma unroll
      for (int g = 0; g < 4; ++g) zpre[g] = biasv[g];
    }

    float acc[8];
#pragma unroll
    for (int rr = 0; rr < 8; ++rr) acc[rr] = 0.f;

    {
      const float* hcur = hT + ((t & 1) << 15);
      const int k0 = kq << 6;
#pragma unroll
      for (int k4 = 0; k4 < 16; ++k4) {
        const int k = k0 + (k4 << 2);
        const float h0 = hcur[(k + 0) * 64 + b];
        const float h1 = hcur[(k + 1) * 64 + b];
        const float h2 = hcur[(k + 2) * 64 + b];
        const float h3 = hcur[(k + 3) * 64 + b];
#pragma unroll
        for (int rr = 0; rr < 8; ++rr) {
          float4 wv = *(const float4*)&Wlds[rr * WC + k];
          acc[rr] = fmaf(h0, wv.x, acc[rr]);
          acc[rr] = fmaf(h1, wv.y, acc[rr]);
          acc[rr] = fmaf(h2, wv.z, acc[rr]);
          acc[rr] = fmaf(h3, wv.w, acc[rr]);
        }
      }
    }
    {
      const float* xt = x + (size_t)t * (64 * 512) + b * 512;
      const int k0 = kq << 6;
#pragma unroll
      for (int k4 = 0; k4 < 16; ++k4) {
        const int k = k0 + (k4 << 2);
        float4 xv = *(const float4*)&xt[k];
#pragma unroll
        for (int rr = 0; rr < 8; ++rr) {
          float4 wv = *(const float4*)&Wlds[rr * WC + 512 + k];
          acc[rr] = fmaf(xv.x, wv.x, acc[rr]);
          acc[rr] = fmaf(xv.y, wv.y, acc[rr]);
          acc[rr] = fmaf(xv.z, wv.z, acc[rr]);
          acc[rr] = fmaf(xv.w, wv.w, acc[rr]);
        }
      }
    }

#pragma unroll
    for (int rr = 0; rr < 8; ++rr)
      zpart[((kq << 3) + rr) * 64 + b] = acc[rr];
    __syncthreads();

    if (tid < 128) {
      const int u = tid >> 6, bb = tid & 63;
      float z[4];
#pragma unroll
      for (int g = 0; g < 4; ++g) {
        const int rr = g * 2 + u;
        float s = zpre[g];
#pragma unroll
        for (int q = 0; q < 8; ++q) s += zpart[((q << 3) + rr) * 64 + bb];
        z[g] = s;
      }
      const float f  = sigf(z[0]);
      const float ig = sigf(z[1]);
      const float o  = sigf(z[2]);
      const float ct = tanhf_(z[3]);
      float cn = f * c_r + ig * ct;
      cn = mval * cn + (1.f - mval) * c_r;
      c_r = cn;
      float hn = o * tanhf_(cn);
      hn = mval * hn + (1.f - mval) * h_r;
      h_r = hn;
      const int n = n0 + u;
      hT[(((t + 1) & 1) << 15) + n * 64 + bb] = hn;
      out[((size_t)t * 64 + bb) * 512 + n]         = hn;
      out[HHIST + ((size_t)t * 64 + bb) * 512 + n] = ig;
    }

    if (t != T_STEPS - 1) grid_barrier(cnt, w, tid, t);
  }
}

// ---------------------------------------------------------------------------
// launch
// ---------------------------------------------------------------------------
extern "C" void kernel_launch(void* const* d_in, const int* in_sizes, int n_in,
                              void* d_out, int out_size, void* d_ws, size_t ws_size,
                              hipStream_t stream) {
  (void)in_sizes; (void)n_in; (void)out_size;
  // setup_inputs order: x, mask, Wf, bf, Wi, bi, Wc, bc, Wo, bo
  const float* x    = (const float*)d_in[0];
  const float* mask = (const float*)d_in[1];
  const float* Wf   = (const float*)d_in[2];
  const float* bf   = (const float*)d_in[3];
  const float* Wi   = (const float*)d_in[4];
  const float* bi   = (const float*)d_in[5];
  const float* Wc   = (const float*)d_in[6];
  const float* bc   = (const float*)d_in[7];
  const float* Wo   = (const float*)d_in[8];
  const float* bo   = (const float*)d_in[9];
  float* out = (float*)d_out;

  const size_t zx_bytes = (size_t)T_STEPS * NROW * 64 * 4;        // 256 MiB
  const size_t hp_bytes = (size_t)2 * 8 * 512 * 8 * 8;            // 512 KiB pairs
  const bool fast = ws_size >= zx_bytes + hp_bytes;

  if (fast) {
    float* Zx = (float*)d_ws;
    unsigned long long* hP = (unsigned long long*)((char*)d_ws + zx_bytes);
    // zero epoch buffer every launch: epoch 0 + h=0 is the t=0 initial state
    hipMemsetAsync(hP, 0, hp_bytes, stream);
    hipLaunchKernelGGL(xgemm_kernel, dim3(16, 512), dim3(256), 0, stream,
                       x, Wf, Wi, Wo, Wc, bf, bi, bo, bc, Zx);
    void* kargs[] = { (void*)&mask, (void*)&Wf, (void*)&Wi, (void*)&Wo,
                      (void*)&Wc, (void*)&Zx, (void*)&hP, (void*)&out };
    hipLaunchCooperativeKernel(reinterpret_cast<void*>(&lstm_rec_fast),
                               dim3(256), dim3(512), kargs, 0, stream);
  } else {
    float* hT = (float*)d_ws;
    const size_t h_bytes = 2 * 64 * 512 * 4;                      // 256 KiB
    unsigned* cnt = (unsigned*)((char*)hT + h_bytes);
    hipMemsetAsync(hT, 0, h_bytes + 4096, stream);
    void* kargs[] = { (void*)&x, (void*)&mask, (void*)&Wf, (void*)&Wi,
                      (void*)&Wo, (void*)&Wc, (void*)&bf, (void*)&bi,
                      (void*)&bo, (void*)&bc, (void*)&hT, (void*)&cnt,
                      (void*)&out };
    hipLaunchCooperativeKernel(reinterpret_cast<void*>(&lstm_rec_inline),
                               dim3(256), dim3(512), kargs, 0, stream);
  }
}